// Round 5
// baseline (1131.231 us; speedup 1.0000x reference)
//
#include <hip/hip_runtime.h>

// Activations: (vertex, batch=16, channel), channel fastest, stored FP16.
// bufA (fp16, cap 25,690,112 B) = conv outputs / x0.
// bufB (fp16, cap 51,380,224 B) = pool outputs (conv inputs).
//
// GEMM numerics: A panel = dwconv(fp32 accum) rounded to fp16; B = split
// hi/lo fp16 (2^-22 weight precision). D = Ah*Bh + Ah*Bl*2^-11.
// Conv epilogue stages the 64xCO fp16 tile in LDS (reusing the A panel) and
// stores with coalesced uint4 writes — avoids 2B-scattered-store RMW traffic.

typedef _Float16 half8 __attribute__((ext_vector_type(8)));
typedef float    f32x4 __attribute__((ext_vector_type(4)));

__device__ __forceinline__ float4 ld4(const float* p) { return *(const float4*)p; }

__device__ __forceinline__ float lo16f(unsigned u) {
  _Float16 h; unsigned short s = (unsigned short)(u & 0xffffu);
  __builtin_memcpy(&h, &s, 2); return (float)h;
}
__device__ __forceinline__ float hi16f(unsigned u) {
  _Float16 h; unsigned short s = (unsigned short)(u >> 16);
  __builtin_memcpy(&h, &s, 2); return (float)h;
}
__device__ __forceinline__ float h2f(unsigned short s) {
  _Float16 h; __builtin_memcpy(&h, &s, 2); return (float)h;
}
__device__ __forceinline__ unsigned short hbits(float v) {
  _Float16 h = (_Float16)v; unsigned short u; __builtin_memcpy(&u, &h, 2); return u;
}
__device__ __forceinline__ unsigned pk2h(float a, float b) {
  return (unsigned)hbits(a) | ((unsigned)hbits(b) << 16);
}
// split v = hi + lo*2^-11, lo pre-scaled by 2048
__device__ __forceinline__ void split2h(float v, unsigned short& h, unsigned short& l) {
  _Float16 hf = (_Float16)v;
  float hif = (float)hf;
  _Float16 lf = (_Float16)((v - hif) * 2048.0f);
  __builtin_memcpy(&h, &hf, 2); __builtin_memcpy(&l, &lf, 2);
}

// ---------------- prep: transpose+split pw -> pwT_hi / pwT_lo fp16 [CO][CI] ----------------
__global__ __launch_bounds__(256) void k_prep(
    const float* __restrict__ pw0, const float* __restrict__ pw1,
    const float* __restrict__ pw2, const float* __restrict__ pw3,
    unsigned short* __restrict__ dst)
{
  const int b = blockIdx.x, t = threadIdx.x;
  const float* src; int ci_sh, co, f, off;
  if (b < 256)      { src = pw0; ci_sh = 8; co = 256; f = b*256 + t;       off = 0; }
  else if (b < 512) { src = pw1; ci_sh = 8; co = 256; f = (b-256)*256 + t; off = 65536; }
  else if (b < 640) { src = pw2; ci_sh = 8; co = 128; f = (b-512)*256 + t; off = 131072; }
  else              { src = pw3; ci_sh = 7; co = 64;  f = (b-640)*256 + t; off = 163840; }
  const int n = f >> ci_sh, k = f & ((1 << ci_sh) - 1);
  float v = src[(size_t)k*co + n];
  unsigned short h, l; split2h(v, h, l);
  dst[off + f]          = h;
  dst[172032 + off + f] = l;
}

// ---------------- fused grid-sample + upsample GEMM -> fp16 x0 ----------------
__global__ __launch_bounds__(256) void k_sample_up(
    const float* __restrict__ uv, const float* __restrict__ feat,
    const float* __restrict__ up, unsigned short* __restrict__ x0)
{
  __shared__ float feat_l[256][17];
  const int tid = threadIdx.x;
  const int b   = blockIdx.y;
  const int v0  = blockIdx.x * 56;

  const float* fr = feat + ((size_t)b*256 + tid)*16;
  #pragma unroll
  for (int i = 0; i < 16; i += 4) {
    float4 f = ld4(fr + i);
    feat_l[tid][i+0] = f.x; feat_l[tid][i+1] = f.y;
    feat_l[tid][i+2] = f.z; feat_l[tid][i+3] = f.w;
  }
  float xg[64];
  #pragma unroll
  for (int p = 0; p < 64; ++p) {
    float gx = uv[((size_t)b*64 + p)*2 + 0];
    float gy = uv[((size_t)b*64 + p)*2 + 1];
    gx = fminf(fmaxf((gx - 0.5f)*2.f, -1.f), 1.f);
    gy = fminf(fmaxf((gy - 0.5f)*2.f, -1.f), 1.f);
    float x = (gx + 1.f)*0.5f*3.f;
    float y = (gy + 1.f)*0.5f*3.f;
    float fx = floorf(x), fy = floorf(y);
    int ix0 = (int)fx, iy0 = (int)fy;
    float wx = x - fx, wy = y - fy;
    int ix1 = ix0 + 1 > 3 ? 3 : ix0 + 1;
    int iy1 = iy0 + 1 > 3 ? 3 : iy0 + 1;
    float v00 = feat_l[tid][iy0*4+ix0];
    float v01 = feat_l[tid][iy0*4+ix1];
    float v10 = feat_l[tid][iy1*4+ix0];
    float v11 = feat_l[tid][iy1*4+ix1];
    xg[p] = (1.f-wy)*((1.f-wx)*v00 + wx*v01) + wy*((1.f-wx)*v10 + wx*v11);
  }
  for (int vv = 0; vv < 56; vv += 4) {
    float a0 = 0.f, a1 = 0.f, a2 = 0.f, a3 = 0.f;
    const float* u0 = up + (size_t)(v0+vv  )*64;
    const float* u1 = up + (size_t)(v0+vv+1)*64;
    const float* u2 = up + (size_t)(v0+vv+2)*64;
    const float* u3 = up + (size_t)(v0+vv+3)*64;
    #pragma unroll
    for (int p = 0; p < 64; ++p) {
      float xv = xg[p];
      a0 += u0[p]*xv; a1 += u1[p]*xv; a2 += u2[p]*xv; a3 += u3[p]*xv;
    }
    unsigned short* o = x0 + ((size_t)(v0+vv)*16 + b)*256 + tid;
    o[0*16*256] = hbits(a0); o[1*16*256] = hbits(a1);
    o[2*16*256] = hbits(a2); o[3*16*256] = hbits(a3);
  }
}

// ---------------- mesh up-pool: fp16 -> fp16 (fp32 math) ----------------
__global__ __launch_bounds__(256) void k_pool(
    const unsigned short* __restrict__ x, const int* __restrict__ col,
    const float* __restrict__ val, unsigned short* __restrict__ out, int C16)
{
  const int v = blockIdx.x;
  const int c0 = col[3*v+0], c1 = col[3*v+1], c2 = col[3*v+2];
  const float w0 = val[3*v+0], w1 = val[3*v+1], w2 = val[3*v+2];
  const uint4* r0 = (const uint4*)(x + (size_t)c0*C16);
  const uint4* r1 = (const uint4*)(x + (size_t)c1*C16);
  const uint4* r2 = (const uint4*)(x + (size_t)c2*C16);
  uint4* o = (uint4*)(out + (size_t)v*C16);
  const int n8 = C16 >> 3;
  for (int i = threadIdx.x; i < n8; i += 256) {
    uint4 A = r0[i], B = r1[i], Cv = r2[i], R;
    R.x = pk2h(w0*lo16f(A.x)+w1*lo16f(B.x)+w2*lo16f(Cv.x),
               w0*hi16f(A.x)+w1*hi16f(B.x)+w2*hi16f(Cv.x));
    R.y = pk2h(w0*lo16f(A.y)+w1*lo16f(B.y)+w2*lo16f(Cv.y),
               w0*hi16f(A.y)+w1*hi16f(B.y)+w2*hi16f(Cv.y));
    R.z = pk2h(w0*lo16f(A.z)+w1*lo16f(B.z)+w2*lo16f(Cv.z),
               w0*hi16f(A.z)+w1*hi16f(B.z)+w2*hi16f(Cv.z));
    R.w = pk2h(w0*lo16f(A.w)+w1*lo16f(B.w)+w2*lo16f(Cv.w),
               w0*hi16f(A.w)+w1*hi16f(B.w)+w2*hi16f(Cv.w));
    o[i] = R;
  }
}

// ---------------- fused spiral-gather + dwconv(fp32) + MFMA pointwise ----------------
// Block = 64 M-rows (4 vertices x 16 batch) x full CO.  A panel (64 x CI fp16)
// built once in LDS; D = Ah*Bh + Ah*Bl*2^-11.  Epilogue stages the fp16
// output tile in the same LDS and stores coalesced uint4.
template<int CI, int CO, bool RELU>
__global__ __launch_bounds__(256, (CI==128) ? 5 : 4) void k_conv(
    const unsigned short* __restrict__ pin, const int* __restrict__ idx,
    const float* __restrict__ dw,
    const unsigned short* __restrict__ bhp, const unsigned short* __restrict__ blp,
    unsigned short* __restrict__ out)
{
  constexpr int KG     = CI/8;      // channel groups of 8 (16B fp16 gather)
  constexpr int MPT    = KG/4;      // rows per thread (64*KG/256)
  constexpr int AROW   = CI + 8;
  constexpr int OROW   = CO + 8;
  constexpr int NTW    = CO/64;
  constexpr int CHUNKS = CI/32;

  __shared__ __align__(16) unsigned short a_l[64][AROW];

  const int t  = threadIdx.x;
  const int v0 = blockIdx.x * 4;

  // ---- build A panel ----
  {
    const int kg   = t & (KG - 1);
    const int mb   = (t / KG) * MPT;
    const int vloc = mb >> 4;          // constant per thread (MPT | 16)
    int rows[9];
    #pragma unroll
    for (int s = 0; s < 9; ++s) rows[s] = idx[(v0 + vloc)*9 + s] * (16*CI);
    float dwv[72];
    #pragma unroll
    for (int j = 0; j < 8; ++j)
      #pragma unroll
      for (int s = 0; s < 9; ++s) dwv[j*9 + s] = dw[(size_t)(8*kg + j)*9 + s];

    #pragma unroll
    for (int i = 0; i < MPT; ++i) {
      const int m = mb + i;
      const unsigned short* base = pin + (size_t)(m & 15)*CI + 8*kg;
      float y[8];
      #pragma unroll
      for (int j = 0; j < 8; ++j) y[j] = 0.f;
      #pragma unroll
      for (int s = 0; s < 9; ++s) {
        const uint4 g = *(const uint4*)(base + rows[s]);
        y[0] += dwv[0*9+s]*lo16f(g.x); y[1] += dwv[1*9+s]*hi16f(g.x);
        y[2] += dwv[2*9+s]*lo16f(g.y); y[3] += dwv[3*9+s]*hi16f(g.y);
        y[4] += dwv[4*9+s]*lo16f(g.z); y[5] += dwv[5*9+s]*hi16f(g.z);
        y[6] += dwv[6*9+s]*lo16f(g.w); y[7] += dwv[7*9+s]*hi16f(g.w);
      }
      uint4 pkd;
      pkd.x = pk2h(y[0], y[1]); pkd.y = pk2h(y[2], y[3]);
      pkd.z = pk2h(y[4], y[5]); pkd.w = pk2h(y[6], y[7]);
      *(uint4*)&a_l[m][8*kg] = pkd;
    }
  }
  __syncthreads();

  // ---- MFMA phase: D = Ah*Bh + Ah*Bl*2^-11 ----
  const int w = t >> 6, l = t & 15, q = (t >> 4) & 3;
  f32x4 ah[4][NTW], ax[4][NTW];
  #pragma unroll
  for (int mt = 0; mt < 4; ++mt)
    #pragma unroll
    for (int n = 0; n < NTW; ++n)
      #pragma unroll
      for (int r = 0; r < 4; ++r) { ah[mt][n][r] = 0.f; ax[mt][n][r] = 0.f; }

  #pragma unroll
  for (int c = 0; c < CHUNKS; ++c) {
    const int k0 = c*32 + q*8;
    half8 fa[4], fbh[NTW], fbl[NTW];
    #pragma unroll
    for (int mt = 0; mt < 4; ++mt)
      fa[mt] = *(const half8*)&a_l[mt*16 + l][k0];
    #pragma unroll
    for (int n = 0; n < NTW; ++n) {
      const size_t boff = (size_t)((w*NTW + n)*16 + l)*CI + k0;
      fbh[n] = *(const half8*)(bhp + boff);
      fbl[n] = *(const half8*)(blp + boff);
    }
    #pragma unroll
    for (int mt = 0; mt < 4; ++mt)
      #pragma unroll
      for (int n = 0; n < NTW; ++n) {
        ah[mt][n] = __builtin_amdgcn_mfma_f32_16x16x32_f16(fa[mt], fbh[n], ah[mt][n], 0, 0, 0);
        ax[mt][n] = __builtin_amdgcn_mfma_f32_16x16x32_f16(fa[mt], fbl[n], ax[mt][n], 0, 0, 0);
      }
  }

  // ---- epilogue: stage fp16 tile in LDS (reuse a_l), then coalesced store ----
  __syncthreads();   // all a_l fragment reads complete
  unsigned short (*ot)[OROW] = (unsigned short (*)[OROW])&a_l[0][0];
  #pragma unroll
  for (int mt = 0; mt < 4; ++mt)
    #pragma unroll
    for (int n = 0; n < NTW; ++n) {
      const int colg = (w*NTW + n)*16 + l;
      #pragma unroll
      for (int r = 0; r < 4; ++r) {
        const int row = mt*16 + q*4 + r;
        float v = ah[mt][n][r] + ax[mt][n][r] * (1.0f/2048.0f);
        if (RELU) v = fmaxf(v, 0.f);
        ot[row][colg] = hbits(v);
      }
    }
  __syncthreads();
  constexpr int PR = CO/8;           // uint4 per output row
  unsigned short* ob = out + (size_t)v0*16*CO;
  #pragma unroll
  for (int i = 0; i < (64*PR)/256; ++i) {
    const int item = t + i*256;
    const int r  = item / PR;
    const int cp = (item % PR)*8;
    *(uint4*)(ob + (size_t)r*CO + cp) = *(const uint4*)&ot[r][cp];
  }
}

// ---------------- head: spiral conv 64 -> 3 (fp32 math), output (b, v, 3) ----------------
__global__ __launch_bounds__(256) void k_head(
    const unsigned short* __restrict__ a, const int* __restrict__ idx,
    const float* __restrict__ dwh, const float* __restrict__ pwh,
    float* __restrict__ out, int nvert)
{
  const int wid  = blockIdx.x*4 + (threadIdx.x >> 6);
  const int lane = threadIdx.x & 63;
  const int v = wid >> 4, b = wid & 15;
  float y = 0.f;
  #pragma unroll
  for (int s = 0; s < 9; ++s) {
    int r = idx[v*9 + s];
    y += dwh[lane*9 + s] * h2f(a[((size_t)r*16 + b)*64 + lane]);
  }
  float p0 = y * pwh[lane*3+0];
  float p1 = y * pwh[lane*3+1];
  float p2 = y * pwh[lane*3+2];
  #pragma unroll
  for (int o = 32; o > 0; o >>= 1) {
    p0 += __shfl_xor(p0, o, 64);
    p1 += __shfl_xor(p1, o, 64);
    p2 += __shfl_xor(p2, o, 64);
  }
  if (lane == 0) {
    size_t off = ((size_t)b*nvert + v)*3;
    out[off+0] = p0; out[off+1] = p1; out[off+2] = p2;
  }
}

extern "C" void kernel_launch(void* const* d_in, const int* in_sizes, int n_in,
                              void* d_out, int out_size, void* d_ws, size_t ws_size,
                              hipStream_t stream)
{
  const float* uv   = (const float*)d_in[0];
  const float* feat = (const float*)d_in[1];
  const float* up   = (const float*)d_in[2];
  const float* dw0  = (const float*)d_in[3];
  const float* pw0  = (const float*)d_in[4];
  const float* dw1  = (const float*)d_in[5];
  const float* pw1  = (const float*)d_in[6];
  const float* dw2  = (const float*)d_in[7];
  const float* pw2  = (const float*)d_in[8];
  const float* dw3  = (const float*)d_in[9];
  const float* pw3  = (const float*)d_in[10];
  const float* dwh  = (const float*)d_in[11];
  const float* pwh  = (const float*)d_in[12];
  const int*   sp0  = (const int*)d_in[13];
  const int*   col0 = (const int*)d_in[14];
  const float* val0 = (const float*)d_in[15];
  const int*   sp1  = (const int*)d_in[16];
  const int*   col1 = (const int*)d_in[17];
  const float* val1 = (const float*)d_in[18];
  const int*   sp2  = (const int*)d_in[19];
  const int*   col2 = (const int*)d_in[20];
  const float* val2 = (const float*)d_in[21];
  const int*   sp3  = (const int*)d_in[22];
  const int*   col3 = (const int*)d_in[23];
  const float* val3 = (const float*)d_in[24];

  unsigned short* bufA = (unsigned short*)d_ws;                      // 25,690,112 B
  unsigned short* bufB = (unsigned short*)((char*)d_ws + 25690112);  // 51,380,224 B
  float* outp = (float*)d_out;

  // split pw tables in d_out scratch (overwritten by k_head at the end)
  unsigned short* pwT = (unsigned short*)d_out;
  unsigned short* h0 = pwT;            unsigned short* L0 = pwT + 172032;
  unsigned short* h1 = pwT + 65536;    unsigned short* L1 = L0 + 65536;
  unsigned short* h2 = pwT + 131072;   unsigned short* L2 = L0 + 131072;
  unsigned short* h3 = pwT + 163840;   unsigned short* L3 = L0 + 163840;

  k_prep<<<672, 256, 0, stream>>>(pw0, pw1, pw2, pw3, pwT);
  k_sample_up<<<dim3(14,16,1), 256, 0, stream>>>(uv, feat, up, bufA);

  k_pool<<<1568, 256, 0, stream>>>(bufA, col3, val3, bufB, 16*256);
  k_conv<256,256,true><<<392, 256, 0, stream>>>(bufB, sp3, dw0, h0, L0, bufA);

  k_pool<<<3136, 256, 0, stream>>>(bufA, col2, val2, bufB, 16*256);
  k_conv<256,256,true><<<784, 256, 0, stream>>>(bufB, sp2, dw1, h1, L1, bufA);

  k_pool<<<6272, 256, 0, stream>>>(bufA, col1, val1, bufB, 16*256);
  k_conv<256,128,true><<<1568, 256, 0, stream>>>(bufB, sp1, dw2, h2, L2, bufA);

  k_pool<<<12544, 256, 0, stream>>>(bufA, col0, val0, bufB, 16*128);
  k_conv<128,64,true><<<3136, 256, 0, stream>>>(bufB, sp0, dw3, h3, L3, bufA);

  k_head<<<50176, 256, 0, stream>>>(bufA, sp0, dwh, pwh, outp, 12544);
}

// Round 6
// 749.082 us; speedup vs baseline: 1.5102x; 1.5102x over previous
//
#include <hip/hip_runtime.h>

// Activations: (vertex, batch=16, channel), channel fastest, stored FP16.
// bufA (fp16, cap 25,690,112 B) = conv outputs / x0.
// bufB (fp16, cap 51,380,224 B) = pool outputs (conv inputs).
//
// GEMM numerics: A panel = dwconv(fp32 accum) rounded to fp16; B = split
// hi/lo fp16 (2^-22 weight precision). D = Ah*Bh + Ah*Bl*2^-11.
// Conv epilogue stages the 64xCO fp16 tile in LDS (reusing the A panel) and
// stores with coalesced uint4 writes.
// NOTE: __launch_bounds__ min-waves kept at 3 (CI=256) / 4 (CI=128): round-5's
// 4/5 forced VGPR 84->64 and caused massive scratch-spill traffic (WRITE_SIZE
// 585 MB, 20 ms dispatches). Do not raise without checking VGPR_Count.

typedef _Float16 half8 __attribute__((ext_vector_type(8)));
typedef float    f32x4 __attribute__((ext_vector_type(4)));

__device__ __forceinline__ float4 ld4(const float* p) { return *(const float4*)p; }

__device__ __forceinline__ float lo16f(unsigned u) {
  _Float16 h; unsigned short s = (unsigned short)(u & 0xffffu);
  __builtin_memcpy(&h, &s, 2); return (float)h;
}
__device__ __forceinline__ float hi16f(unsigned u) {
  _Float16 h; unsigned short s = (unsigned short)(u >> 16);
  __builtin_memcpy(&h, &s, 2); return (float)h;
}
__device__ __forceinline__ float h2f(unsigned short s) {
  _Float16 h; __builtin_memcpy(&h, &s, 2); return (float)h;
}
__device__ __forceinline__ unsigned short hbits(float v) {
  _Float16 h = (_Float16)v; unsigned short u; __builtin_memcpy(&u, &h, 2); return u;
}
__device__ __forceinline__ unsigned pk2h(float a, float b) {
  return (unsigned)hbits(a) | ((unsigned)hbits(b) << 16);
}
// split v = hi + lo*2^-11, lo pre-scaled by 2048
__device__ __forceinline__ void split2h(float v, unsigned short& h, unsigned short& l) {
  _Float16 hf = (_Float16)v;
  float hif = (float)hf;
  _Float16 lf = (_Float16)((v - hif) * 2048.0f);
  __builtin_memcpy(&h, &hf, 2); __builtin_memcpy(&l, &lf, 2);
}

// ---------------- prep: transpose+split pw -> pwT_hi / pwT_lo fp16 [CO][CI] ----------------
__global__ __launch_bounds__(256) void k_prep(
    const float* __restrict__ pw0, const float* __restrict__ pw1,
    const float* __restrict__ pw2, const float* __restrict__ pw3,
    unsigned short* __restrict__ dst)
{
  const int b = blockIdx.x, t = threadIdx.x;
  const float* src; int ci_sh, co, f, off;
  if (b < 256)      { src = pw0; ci_sh = 8; co = 256; f = b*256 + t;       off = 0; }
  else if (b < 512) { src = pw1; ci_sh = 8; co = 256; f = (b-256)*256 + t; off = 65536; }
  else if (b < 640) { src = pw2; ci_sh = 8; co = 128; f = (b-512)*256 + t; off = 131072; }
  else              { src = pw3; ci_sh = 7; co = 64;  f = (b-640)*256 + t; off = 163840; }
  const int n = f >> ci_sh, k = f & ((1 << ci_sh) - 1);
  float v = src[(size_t)k*co + n];
  unsigned short h, l; split2h(v, h, l);
  dst[off + f]          = h;
  dst[172032 + off + f] = l;
}

// ---------------- fused grid-sample + upsample GEMM -> fp16 x0 ----------------
__global__ __launch_bounds__(256) void k_sample_up(
    const float* __restrict__ uv, const float* __restrict__ feat,
    const float* __restrict__ up, unsigned short* __restrict__ x0)
{
  __shared__ float feat_l[256][17];
  const int tid = threadIdx.x;
  const int b   = blockIdx.y;
  const int v0  = blockIdx.x * 56;

  const float* fr = feat + ((size_t)b*256 + tid)*16;
  #pragma unroll
  for (int i = 0; i < 16; i += 4) {
    float4 f = ld4(fr + i);
    feat_l[tid][i+0] = f.x; feat_l[tid][i+1] = f.y;
    feat_l[tid][i+2] = f.z; feat_l[tid][i+3] = f.w;
  }
  float xg[64];
  #pragma unroll
  for (int p = 0; p < 64; ++p) {
    float gx = uv[((size_t)b*64 + p)*2 + 0];
    float gy = uv[((size_t)b*64 + p)*2 + 1];
    gx = fminf(fmaxf((gx - 0.5f)*2.f, -1.f), 1.f);
    gy = fminf(fmaxf((gy - 0.5f)*2.f, -1.f), 1.f);
    float x = (gx + 1.f)*0.5f*3.f;
    float y = (gy + 1.f)*0.5f*3.f;
    float fx = floorf(x), fy = floorf(y);
    int ix0 = (int)fx, iy0 = (int)fy;
    float wx = x - fx, wy = y - fy;
    int ix1 = ix0 + 1 > 3 ? 3 : ix0 + 1;
    int iy1 = iy0 + 1 > 3 ? 3 : iy0 + 1;
    float v00 = feat_l[tid][iy0*4+ix0];
    float v01 = feat_l[tid][iy0*4+ix1];
    float v10 = feat_l[tid][iy1*4+ix0];
    float v11 = feat_l[tid][iy1*4+ix1];
    xg[p] = (1.f-wy)*((1.f-wx)*v00 + wx*v01) + wy*((1.f-wx)*v10 + wx*v11);
  }
  for (int vv = 0; vv < 56; vv += 4) {
    float a0 = 0.f, a1 = 0.f, a2 = 0.f, a3 = 0.f;
    const float* u0 = up + (size_t)(v0+vv  )*64;
    const float* u1 = up + (size_t)(v0+vv+1)*64;
    const float* u2 = up + (size_t)(v0+vv+2)*64;
    const float* u3 = up + (size_t)(v0+vv+3)*64;
    #pragma unroll
    for (int p = 0; p < 64; ++p) {
      float xv = xg[p];
      a0 += u0[p]*xv; a1 += u1[p]*xv; a2 += u2[p]*xv; a3 += u3[p]*xv;
    }
    unsigned short* o = x0 + ((size_t)(v0+vv)*16 + b)*256 + tid;
    o[0*16*256] = hbits(a0); o[1*16*256] = hbits(a1);
    o[2*16*256] = hbits(a2); o[3*16*256] = hbits(a3);
  }
}

// ---------------- mesh up-pool: fp16 -> fp16 (fp32 math) ----------------
__global__ __launch_bounds__(256) void k_pool(
    const unsigned short* __restrict__ x, const int* __restrict__ col,
    const float* __restrict__ val, unsigned short* __restrict__ out, int C16)
{
  const int v = blockIdx.x;
  const int c0 = col[3*v+0], c1 = col[3*v+1], c2 = col[3*v+2];
  const float w0 = val[3*v+0], w1 = val[3*v+1], w2 = val[3*v+2];
  const uint4* r0 = (const uint4*)(x + (size_t)c0*C16);
  const uint4* r1 = (const uint4*)(x + (size_t)c1*C16);
  const uint4* r2 = (const uint4*)(x + (size_t)c2*C16);
  uint4* o = (uint4*)(out + (size_t)v*C16);
  const int n8 = C16 >> 3;
  for (int i = threadIdx.x; i < n8; i += 256) {
    uint4 A = r0[i], B = r1[i], Cv = r2[i], R;
    R.x = pk2h(w0*lo16f(A.x)+w1*lo16f(B.x)+w2*lo16f(Cv.x),
               w0*hi16f(A.x)+w1*hi16f(B.x)+w2*hi16f(Cv.x));
    R.y = pk2h(w0*lo16f(A.y)+w1*lo16f(B.y)+w2*lo16f(Cv.y),
               w0*hi16f(A.y)+w1*hi16f(B.y)+w2*hi16f(Cv.y));
    R.z = pk2h(w0*lo16f(A.z)+w1*lo16f(B.z)+w2*lo16f(Cv.z),
               w0*hi16f(A.z)+w1*hi16f(B.z)+w2*hi16f(Cv.z));
    R.w = pk2h(w0*lo16f(A.w)+w1*lo16f(B.w)+w2*lo16f(Cv.w),
               w0*hi16f(A.w)+w1*hi16f(B.w)+w2*hi16f(Cv.w));
    o[i] = R;
  }
}

// ---------------- fused spiral-gather + dwconv(fp32) + MFMA pointwise ----------------
// Block = 64 M-rows (4 vertices x 16 batch) x full CO.  A panel (64 x CI fp16)
// built once in LDS; D = Ah*Bh + Ah*Bl*2^-11.  Epilogue stages the fp16
// output tile in the same LDS and stores coalesced uint4.
template<int CI, int CO, bool RELU>
__global__ __launch_bounds__(256, (CI==128) ? 4 : 3) void k_conv(
    const unsigned short* __restrict__ pin, const int* __restrict__ idx,
    const float* __restrict__ dw,
    const unsigned short* __restrict__ bhp, const unsigned short* __restrict__ blp,
    unsigned short* __restrict__ out)
{
  constexpr int KG     = CI/8;      // channel groups of 8 (16B fp16 gather)
  constexpr int MPT    = KG/4;      // rows per thread (64*KG/256)
  constexpr int AROW   = CI + 8;
  constexpr int OROW   = CO + 8;
  constexpr int NTW    = CO/64;
  constexpr int CHUNKS = CI/32;

  __shared__ __align__(16) unsigned short a_l[64][AROW];

  const int t  = threadIdx.x;
  const int v0 = blockIdx.x * 4;

  // ---- build A panel ----
  {
    const int kg   = t & (KG - 1);
    const int mb   = (t / KG) * MPT;
    const int vloc = mb >> 4;          // constant per thread (MPT | 16)
    int rows[9];
    #pragma unroll
    for (int s = 0; s < 9; ++s) rows[s] = idx[(v0 + vloc)*9 + s] * (16*CI);
    float dwv[72];
    #pragma unroll
    for (int j = 0; j < 8; ++j)
      #pragma unroll
      for (int s = 0; s < 9; ++s) dwv[j*9 + s] = dw[(size_t)(8*kg + j)*9 + s];

    #pragma unroll
    for (int i = 0; i < MPT; ++i) {
      const int m = mb + i;
      const unsigned short* base = pin + (size_t)(m & 15)*CI + 8*kg;
      float y[8];
      #pragma unroll
      for (int j = 0; j < 8; ++j) y[j] = 0.f;
      #pragma unroll
      for (int s = 0; s < 9; ++s) {
        const uint4 g = *(const uint4*)(base + rows[s]);
        y[0] += dwv[0*9+s]*lo16f(g.x); y[1] += dwv[1*9+s]*hi16f(g.x);
        y[2] += dwv[2*9+s]*lo16f(g.y); y[3] += dwv[3*9+s]*hi16f(g.y);
        y[4] += dwv[4*9+s]*lo16f(g.z); y[5] += dwv[5*9+s]*hi16f(g.z);
        y[6] += dwv[6*9+s]*lo16f(g.w); y[7] += dwv[7*9+s]*hi16f(g.w);
      }
      uint4 pkd;
      pkd.x = pk2h(y[0], y[1]); pkd.y = pk2h(y[2], y[3]);
      pkd.z = pk2h(y[4], y[5]); pkd.w = pk2h(y[6], y[7]);
      *(uint4*)&a_l[m][8*kg] = pkd;
    }
  }
  __syncthreads();

  // ---- MFMA phase: D = Ah*Bh + Ah*Bl*2^-11 ----
  const int w = t >> 6, l = t & 15, q = (t >> 4) & 3;
  f32x4 ah[4][NTW], ax[4][NTW];
  #pragma unroll
  for (int mt = 0; mt < 4; ++mt)
    #pragma unroll
    for (int n = 0; n < NTW; ++n)
      #pragma unroll
      for (int r = 0; r < 4; ++r) { ah[mt][n][r] = 0.f; ax[mt][n][r] = 0.f; }

  #pragma unroll
  for (int c = 0; c < CHUNKS; ++c) {
    const int k0 = c*32 + q*8;
    half8 fa[4], fbh[NTW], fbl[NTW];
    #pragma unroll
    for (int mt = 0; mt < 4; ++mt)
      fa[mt] = *(const half8*)&a_l[mt*16 + l][k0];
    #pragma unroll
    for (int n = 0; n < NTW; ++n) {
      const size_t boff = (size_t)((w*NTW + n)*16 + l)*CI + k0;
      fbh[n] = *(const half8*)(bhp + boff);
      fbl[n] = *(const half8*)(blp + boff);
    }
    #pragma unroll
    for (int mt = 0; mt < 4; ++mt)
      #pragma unroll
      for (int n = 0; n < NTW; ++n) {
        ah[mt][n] = __builtin_amdgcn_mfma_f32_16x16x32_f16(fa[mt], fbh[n], ah[mt][n], 0, 0, 0);
        ax[mt][n] = __builtin_amdgcn_mfma_f32_16x16x32_f16(fa[mt], fbl[n], ax[mt][n], 0, 0, 0);
      }
  }

  // ---- epilogue: stage fp16 tile in LDS (reuse a_l), then coalesced store ----
  __syncthreads();   // all a_l fragment reads complete
  unsigned short (*ot)[OROW] = (unsigned short (*)[OROW])&a_l[0][0];
  #pragma unroll
  for (int mt = 0; mt < 4; ++mt)
    #pragma unroll
    for (int n = 0; n < NTW; ++n) {
      const int colg = (w*NTW + n)*16 + l;
      #pragma unroll
      for (int r = 0; r < 4; ++r) {
        const int row = mt*16 + q*4 + r;
        float v = ah[mt][n][r] + ax[mt][n][r] * (1.0f/2048.0f);
        if (RELU) v = fmaxf(v, 0.f);
        ot[row][colg] = hbits(v);
      }
    }
  __syncthreads();
  constexpr int PR = CO/8;           // uint4 per output row
  unsigned short* ob = out + (size_t)v0*16*CO;
  #pragma unroll
  for (int i = 0; i < (64*PR)/256; ++i) {
    const int item = t + i*256;
    const int r  = item / PR;
    const int cp = (item % PR)*8;
    *(uint4*)(ob + (size_t)r*CO + cp) = *(const uint4*)&ot[r][cp];
  }
}

// ---------------- head: spiral conv 64 -> 3 (fp32 math), output (b, v, 3) ----------------
__global__ __launch_bounds__(256) void k_head(
    const unsigned short* __restrict__ a, const int* __restrict__ idx,
    const float* __restrict__ dwh, const float* __restrict__ pwh,
    float* __restrict__ out, int nvert)
{
  const int wid  = blockIdx.x*4 + (threadIdx.x >> 6);
  const int lane = threadIdx.x & 63;
  const int v = wid >> 4, b = wid & 15;
  float y = 0.f;
  #pragma unroll
  for (int s = 0; s < 9; ++s) {
    int r = idx[v*9 + s];
    y += dwh[lane*9 + s] * h2f(a[((size_t)r*16 + b)*64 + lane]);
  }
  float p0 = y * pwh[lane*3+0];
  float p1 = y * pwh[lane*3+1];
  float p2 = y * pwh[lane*3+2];
  #pragma unroll
  for (int o = 32; o > 0; o >>= 1) {
    p0 += __shfl_xor(p0, o, 64);
    p1 += __shfl_xor(p1, o, 64);
    p2 += __shfl_xor(p2, o, 64);
  }
  if (lane == 0) {
    size_t off = ((size_t)b*nvert + v)*3;
    out[off+0] = p0; out[off+1] = p1; out[off+2] = p2;
  }
}

extern "C" void kernel_launch(void* const* d_in, const int* in_sizes, int n_in,
                              void* d_out, int out_size, void* d_ws, size_t ws_size,
                              hipStream_t stream)
{
  const float* uv   = (const float*)d_in[0];
  const float* feat = (const float*)d_in[1];
  const float* up   = (const float*)d_in[2];
  const float* dw0  = (const float*)d_in[3];
  const float* pw0  = (const float*)d_in[4];
  const float* dw1  = (const float*)d_in[5];
  const float* pw1  = (const float*)d_in[6];
  const float* dw2  = (const float*)d_in[7];
  const float* pw2  = (const float*)d_in[8];
  const float* dw3  = (const float*)d_in[9];
  const float* pw3  = (const float*)d_in[10];
  const float* dwh  = (const float*)d_in[11];
  const float* pwh  = (const float*)d_in[12];
  const int*   sp0  = (const int*)d_in[13];
  const int*   col0 = (const int*)d_in[14];
  const float* val0 = (const float*)d_in[15];
  const int*   sp1  = (const int*)d_in[16];
  const int*   col1 = (const int*)d_in[17];
  const float* val1 = (const float*)d_in[18];
  const int*   sp2  = (const int*)d_in[19];
  const int*   col2 = (const int*)d_in[20];
  const float* val2 = (const float*)d_in[21];
  const int*   sp3  = (const int*)d_in[22];
  const int*   col3 = (const int*)d_in[23];
  const float* val3 = (const float*)d_in[24];

  unsigned short* bufA = (unsigned short*)d_ws;                      // 25,690,112 B
  unsigned short* bufB = (unsigned short*)((char*)d_ws + 25690112);  // 51,380,224 B
  float* outp = (float*)d_out;

  // split pw tables in d_out scratch (overwritten by k_head at the end)
  unsigned short* pwT = (unsigned short*)d_out;
  unsigned short* h0 = pwT;            unsigned short* L0 = pwT + 172032;
  unsigned short* h1 = pwT + 65536;    unsigned short* L1 = L0 + 65536;
  unsigned short* h2 = pwT + 131072;   unsigned short* L2 = L0 + 131072;
  unsigned short* h3 = pwT + 163840;   unsigned short* L3 = L0 + 163840;

  k_prep<<<672, 256, 0, stream>>>(pw0, pw1, pw2, pw3, pwT);
  k_sample_up<<<dim3(14,16,1), 256, 0, stream>>>(uv, feat, up, bufA);

  k_pool<<<1568, 256, 0, stream>>>(bufA, col3, val3, bufB, 16*256);
  k_conv<256,256,true><<<392, 256, 0, stream>>>(bufB, sp3, dw0, h0, L0, bufA);

  k_pool<<<3136, 256, 0, stream>>>(bufA, col2, val2, bufB, 16*256);
  k_conv<256,256,true><<<784, 256, 0, stream>>>(bufB, sp2, dw1, h1, L1, bufA);

  k_pool<<<6272, 256, 0, stream>>>(bufA, col1, val1, bufB, 16*256);
  k_conv<256,128,true><<<1568, 256, 0, stream>>>(bufB, sp1, dw2, h2, L2, bufA);

  k_pool<<<12544, 256, 0, stream>>>(bufA, col0, val0, bufB, 16*128);
  k_conv<128,64,true><<<3136, 256, 0, stream>>>(bufB, sp0, dw3, h3, L3, bufA);

  k_head<<<50176, 256, 0, stream>>>(bufA, sp0, dwh, pwh, outp, 12544);
}

// Round 7
// 647.503 us; speedup vs baseline: 1.7471x; 1.1569x over previous
//
#include <hip/hip_runtime.h>

// Activations: (vertex, batch=16, channel), channel fastest, stored FP16.
// d_ws layout:
//   bufA (fp16, conv outputs / x0)  @ 0          cap 25,690,112 B
//   bufB (fp16, pool outputs)       @ 25,690,112 cap 51,380,224 B
//   bufC (fp16, dwconv A panels)    @ 77,070,336 cap 51,380,224 B
//   pwT  (fp16 split hi/lo tables)  @ 128,450,560  688,128 B
// Total 129.1 MB (ws >= 154 MB proven in round 1).
//
// Conv is SPLIT: k_dw (gather+depthwise, low-VGPR, high-occupancy, coalesced
// panel store) + k_gemm (streaming MFMA, D = Ah*Bh + Ah*Bl*2^-11).
// NOTE: never raise __launch_bounds__ min-waves on the MFMA kernel — round 5
// showed it forces spills (WRITE_SIZE 585 MB, 20 ms dispatches).

typedef _Float16 half8 __attribute__((ext_vector_type(8)));
typedef float    f32x4 __attribute__((ext_vector_type(4)));

__device__ __forceinline__ float4 ld4(const float* p) { return *(const float4*)p; }

__device__ __forceinline__ float lo16f(unsigned u) {
  _Float16 h; unsigned short s = (unsigned short)(u & 0xffffu);
  __builtin_memcpy(&h, &s, 2); return (float)h;
}
__device__ __forceinline__ float hi16f(unsigned u) {
  _Float16 h; unsigned short s = (unsigned short)(u >> 16);
  __builtin_memcpy(&h, &s, 2); return (float)h;
}
__device__ __forceinline__ float h2f(unsigned short s) {
  _Float16 h; __builtin_memcpy(&h, &s, 2); return (float)h;
}
__device__ __forceinline__ unsigned short hbits(float v) {
  _Float16 h = (_Float16)v; unsigned short u; __builtin_memcpy(&u, &h, 2); return u;
}
__device__ __forceinline__ unsigned pk2h(float a, float b) {
  return (unsigned)hbits(a) | ((unsigned)hbits(b) << 16);
}
// split v = hi + lo*2^-11, lo pre-scaled by 2048
__device__ __forceinline__ void split2h(float v, unsigned short& h, unsigned short& l) {
  _Float16 hf = (_Float16)v;
  float hif = (float)hf;
  _Float16 lf = (_Float16)((v - hif) * 2048.0f);
  __builtin_memcpy(&h, &hf, 2); __builtin_memcpy(&l, &lf, 2);
}

// ---------------- prep: transpose+split pw -> pwT_hi / pwT_lo fp16 [CO][CI] ----------------
__global__ __launch_bounds__(256) void k_prep(
    const float* __restrict__ pw0, const float* __restrict__ pw1,
    const float* __restrict__ pw2, const float* __restrict__ pw3,
    unsigned short* __restrict__ dst)
{
  const int b = blockIdx.x, t = threadIdx.x;
  const float* src; int ci_sh, co, f, off;
  if (b < 256)      { src = pw0; ci_sh = 8; co = 256; f = b*256 + t;       off = 0; }
  else if (b < 512) { src = pw1; ci_sh = 8; co = 256; f = (b-256)*256 + t; off = 65536; }
  else if (b < 640) { src = pw2; ci_sh = 8; co = 128; f = (b-512)*256 + t; off = 131072; }
  else              { src = pw3; ci_sh = 7; co = 64;  f = (b-640)*256 + t; off = 163840; }
  const int n = f >> ci_sh, k = f & ((1 << ci_sh) - 1);
  float v = src[(size_t)k*co + n];
  unsigned short h, l; split2h(v, h, l);
  dst[off + f]          = h;
  dst[172032 + off + f] = l;
}

// ---------------- fused grid-sample + upsample GEMM -> fp16 x0 ----------------
__global__ __launch_bounds__(256) void k_sample_up(
    const float* __restrict__ uv, const float* __restrict__ feat,
    const float* __restrict__ up, unsigned short* __restrict__ x0)
{
  __shared__ float feat_l[256][17];
  const int tid = threadIdx.x;
  const int b   = blockIdx.y;
  const int v0  = blockIdx.x * 56;

  const float* fr = feat + ((size_t)b*256 + tid)*16;
  #pragma unroll
  for (int i = 0; i < 16; i += 4) {
    float4 f = ld4(fr + i);
    feat_l[tid][i+0] = f.x; feat_l[tid][i+1] = f.y;
    feat_l[tid][i+2] = f.z; feat_l[tid][i+3] = f.w;
  }
  float xg[64];
  #pragma unroll
  for (int p = 0; p < 64; ++p) {
    float gx = uv[((size_t)b*64 + p)*2 + 0];
    float gy = uv[((size_t)b*64 + p)*2 + 1];
    gx = fminf(fmaxf((gx - 0.5f)*2.f, -1.f), 1.f);
    gy = fminf(fmaxf((gy - 0.5f)*2.f, -1.f), 1.f);
    float x = (gx + 1.f)*0.5f*3.f;
    float y = (gy + 1.f)*0.5f*3.f;
    float fx = floorf(x), fy = floorf(y);
    int ix0 = (int)fx, iy0 = (int)fy;
    float wx = x - fx, wy = y - fy;
    int ix1 = ix0 + 1 > 3 ? 3 : ix0 + 1;
    int iy1 = iy0 + 1 > 3 ? 3 : iy0 + 1;
    float v00 = feat_l[tid][iy0*4+ix0];
    float v01 = feat_l[tid][iy0*4+ix1];
    float v10 = feat_l[tid][iy1*4+ix0];
    float v11 = feat_l[tid][iy1*4+ix1];
    xg[p] = (1.f-wy)*((1.f-wx)*v00 + wx*v01) + wy*((1.f-wx)*v10 + wx*v11);
  }
  for (int vv = 0; vv < 56; vv += 4) {
    float a0 = 0.f, a1 = 0.f, a2 = 0.f, a3 = 0.f;
    const float* u0 = up + (size_t)(v0+vv  )*64;
    const float* u1 = up + (size_t)(v0+vv+1)*64;
    const float* u2 = up + (size_t)(v0+vv+2)*64;
    const float* u3 = up + (size_t)(v0+vv+3)*64;
    #pragma unroll
    for (int p = 0; p < 64; ++p) {
      float xv = xg[p];
      a0 += u0[p]*xv; a1 += u1[p]*xv; a2 += u2[p]*xv; a3 += u3[p]*xv;
    }
    unsigned short* o = x0 + ((size_t)(v0+vv)*16 + b)*256 + tid;
    o[0*16*256] = hbits(a0); o[1*16*256] = hbits(a1);
    o[2*16*256] = hbits(a2); o[3*16*256] = hbits(a3);
  }
}

// ---------------- mesh up-pool: fp16 -> fp16 (fp32 math) ----------------
__global__ __launch_bounds__(256) void k_pool(
    const unsigned short* __restrict__ x, const int* __restrict__ col,
    const float* __restrict__ val, unsigned short* __restrict__ out, int C16)
{
  const int v = blockIdx.x;
  const int c0 = col[3*v+0], c1 = col[3*v+1], c2 = col[3*v+2];
  const float w0 = val[3*v+0], w1 = val[3*v+1], w2 = val[3*v+2];
  const uint4* r0 = (const uint4*)(x + (size_t)c0*C16);
  const uint4* r1 = (const uint4*)(x + (size_t)c1*C16);
  const uint4* r2 = (const uint4*)(x + (size_t)c2*C16);
  uint4* o = (uint4*)(out + (size_t)v*C16);
  const int n8 = C16 >> 3;
  for (int i = threadIdx.x; i < n8; i += 256) {
    uint4 A = r0[i], B = r1[i], Cv = r2[i], R;
    R.x = pk2h(w0*lo16f(A.x)+w1*lo16f(B.x)+w2*lo16f(Cv.x),
               w0*hi16f(A.x)+w1*hi16f(B.x)+w2*hi16f(Cv.x));
    R.y = pk2h(w0*lo16f(A.y)+w1*lo16f(B.y)+w2*lo16f(Cv.y),
               w0*hi16f(A.y)+w1*hi16f(B.y)+w2*hi16f(Cv.y));
    R.z = pk2h(w0*lo16f(A.z)+w1*lo16f(B.z)+w2*lo16f(Cv.z),
               w0*hi16f(A.z)+w1*hi16f(B.z)+w2*hi16f(Cv.z));
    R.w = pk2h(w0*lo16f(A.w)+w1*lo16f(B.w)+w2*lo16f(Cv.w),
               w0*hi16f(A.w)+w1*hi16f(B.w)+w2*hi16f(Cv.w));
    o[i] = R;
  }
}

// ---------------- k_dw: spiral-gather + depthwise conv -> A panel (fp16) ----------------
// Block = 4 vertices x 16 batch = 64 rows x CI.  Gathers into LDS, then
// coalesced uint4 store of the whole panel.  No MFMA -> high occupancy.
template<int CI>
__global__ __launch_bounds__(256) void k_dw(
    const unsigned short* __restrict__ pin, const int* __restrict__ idx,
    const float* __restrict__ dw, unsigned short* __restrict__ aout)
{
  constexpr int KG   = CI/8;      // channel groups of 8 (16B fp16 gather)
  constexpr int MPT  = KG/4;      // rows per thread
  constexpr int AROW = CI + 8;

  __shared__ __align__(16) unsigned short a_l[64][AROW];

  const int t  = threadIdx.x;
  const int v0 = blockIdx.x * 4;

  {
    const int kg   = t & (KG - 1);
    const int mb   = (t / KG) * MPT;
    const int vloc = mb >> 4;
    int rows[9];
    #pragma unroll
    for (int s = 0; s < 9; ++s) rows[s] = idx[(v0 + vloc)*9 + s] * (16*CI);
    float dwv[72];
    #pragma unroll
    for (int j = 0; j < 8; ++j)
      #pragma unroll
      for (int s = 0; s < 9; ++s) dwv[j*9 + s] = dw[(size_t)(8*kg + j)*9 + s];

    #pragma unroll
    for (int i = 0; i < MPT; ++i) {
      const int m = mb + i;
      const unsigned short* base = pin + (size_t)(m & 15)*CI + 8*kg;
      float y[8];
      #pragma unroll
      for (int j = 0; j < 8; ++j) y[j] = 0.f;
      #pragma unroll
      for (int s = 0; s < 9; ++s) {
        const uint4 g = *(const uint4*)(base + rows[s]);
        y[0] += dwv[0*9+s]*lo16f(g.x); y[1] += dwv[1*9+s]*hi16f(g.x);
        y[2] += dwv[2*9+s]*lo16f(g.y); y[3] += dwv[3*9+s]*hi16f(g.y);
        y[4] += dwv[4*9+s]*lo16f(g.z); y[5] += dwv[5*9+s]*hi16f(g.z);
        y[6] += dwv[6*9+s]*lo16f(g.w); y[7] += dwv[7*9+s]*hi16f(g.w);
      }
      uint4 pkd;
      pkd.x = pk2h(y[0], y[1]); pkd.y = pk2h(y[2], y[3]);
      pkd.z = pk2h(y[4], y[5]); pkd.w = pk2h(y[6], y[7]);
      *(uint4*)&a_l[m][8*kg] = pkd;
    }
  }
  __syncthreads();

  // coalesced panel store: 64 rows x CI ushorts
  constexpr int PR = CI/8;  // uint4 per row
  unsigned short* ob = aout + (size_t)v0*16*CI;
  #pragma unroll
  for (int i = 0; i < (64*PR)/256; ++i) {
    const int item = t + i*256;
    const int r  = item / PR;
    const int cp = (item % PR)*8;
    *(uint4*)(ob + (size_t)r*CI + cp) = *(const uint4*)&a_l[r][cp];
  }
}

// ---------------- k_gemm: streaming MFMA pointwise, D = Ah*Bh + Ah*Bl*2^-11 ----------------
// Block = 64 M-rows x full CO.  A read sequentially from the materialized
// panel; B hi/lo L2-resident.  LDS-staged coalesced fp16 output store.
template<int CI, int CO, bool RELU>
__global__ __launch_bounds__(256) void k_gemm(
    const unsigned short* __restrict__ A,
    const unsigned short* __restrict__ bhp, const unsigned short* __restrict__ blp,
    unsigned short* __restrict__ out)
{
  constexpr int NTW    = CO/64;
  constexpr int CHUNKS = CI/32;
  constexpr int OROW   = CO + 8;

  __shared__ __align__(16) unsigned short ot[64][OROW];

  const int t  = threadIdx.x;
  const size_t m0 = (size_t)blockIdx.x * 64;
  const int w = t >> 6, l = t & 15, q = (t >> 4) & 3;

  f32x4 ah[4][NTW], ax[4][NTW];
  #pragma unroll
  for (int mt = 0; mt < 4; ++mt)
    #pragma unroll
    for (int n = 0; n < NTW; ++n)
      #pragma unroll
      for (int r = 0; r < 4; ++r) { ah[mt][n][r] = 0.f; ax[mt][n][r] = 0.f; }

  #pragma unroll
  for (int c = 0; c < CHUNKS; ++c) {
    const int k0 = c*32 + q*8;
    half8 fa[4], fbh[NTW], fbl[NTW];
    #pragma unroll
    for (int mt = 0; mt < 4; ++mt)
      fa[mt] = *(const half8*)(A + (m0 + mt*16 + l)*CI + k0);
    #pragma unroll
    for (int n = 0; n < NTW; ++n) {
      const size_t boff = (size_t)((w*NTW + n)*16 + l)*CI + k0;
      fbh[n] = *(const half8*)(bhp + boff);
      fbl[n] = *(const half8*)(blp + boff);
    }
    #pragma unroll
    for (int mt = 0; mt < 4; ++mt)
      #pragma unroll
      for (int n = 0; n < NTW; ++n) {
        ah[mt][n] = __builtin_amdgcn_mfma_f32_16x16x32_f16(fa[mt], fbh[n], ah[mt][n], 0, 0, 0);
        ax[mt][n] = __builtin_amdgcn_mfma_f32_16x16x32_f16(fa[mt], fbl[n], ax[mt][n], 0, 0, 0);
      }
  }

  // epilogue: D[row=q*4+r][col=lane&15] -> LDS -> coalesced uint4 store
  #pragma unroll
  for (int mt = 0; mt < 4; ++mt)
    #pragma unroll
    for (int n = 0; n < NTW; ++n) {
      const int colg = (w*NTW + n)*16 + l;
      #pragma unroll
      for (int r = 0; r < 4; ++r) {
        const int row = mt*16 + q*4 + r;
        float v = ah[mt][n][r] + ax[mt][n][r] * (1.0f/2048.0f);
        if (RELU) v = fmaxf(v, 0.f);
        ot[row][colg] = hbits(v);
      }
    }
  __syncthreads();
  constexpr int PR = CO/8;
  unsigned short* ob = out + m0*CO;
  #pragma unroll
  for (int i = 0; i < (64*PR)/256; ++i) {
    const int item = t + i*256;
    const int r  = item / PR;
    const int cp = (item % PR)*8;
    *(uint4*)(ob + (size_t)r*CO + cp) = *(const uint4*)&ot[r][cp];
  }
}

// ---------------- head: spiral conv 64 -> 3 (fp32 math), output (b, v, 3) ----------------
__global__ __launch_bounds__(256) void k_head(
    const unsigned short* __restrict__ a, const int* __restrict__ idx,
    const float* __restrict__ dwh, const float* __restrict__ pwh,
    float* __restrict__ out, int nvert)
{
  const int wid  = blockIdx.x*4 + (threadIdx.x >> 6);
  const int lane = threadIdx.x & 63;
  const int v = wid >> 4, b = wid & 15;
  float y = 0.f;
  #pragma unroll
  for (int s = 0; s < 9; ++s) {
    int r = idx[v*9 + s];
    y += dwh[lane*9 + s] * h2f(a[((size_t)r*16 + b)*64 + lane]);
  }
  float p0 = y * pwh[lane*3+0];
  float p1 = y * pwh[lane*3+1];
  float p2 = y * pwh[lane*3+2];
  #pragma unroll
  for (int o = 32; o > 0; o >>= 1) {
    p0 += __shfl_xor(p0, o, 64);
    p1 += __shfl_xor(p1, o, 64);
    p2 += __shfl_xor(p2, o, 64);
  }
  if (lane == 0) {
    size_t off = ((size_t)b*nvert + v)*3;
    out[off+0] = p0; out[off+1] = p1; out[off+2] = p2;
  }
}

extern "C" void kernel_launch(void* const* d_in, const int* in_sizes, int n_in,
                              void* d_out, int out_size, void* d_ws, size_t ws_size,
                              hipStream_t stream)
{
  const float* uv   = (const float*)d_in[0];
  const float* feat = (const float*)d_in[1];
  const float* up   = (const float*)d_in[2];
  const float* dw0  = (const float*)d_in[3];
  const float* pw0  = (const float*)d_in[4];
  const float* dw1  = (const float*)d_in[5];
  const float* pw1  = (const float*)d_in[6];
  const float* dw2  = (const float*)d_in[7];
  const float* pw2  = (const float*)d_in[8];
  const float* dw3  = (const float*)d_in[9];
  const float* pw3  = (const float*)d_in[10];
  const float* dwh  = (const float*)d_in[11];
  const float* pwh  = (const float*)d_in[12];
  const int*   sp0  = (const int*)d_in[13];
  const int*   col0 = (const int*)d_in[14];
  const float* val0 = (const float*)d_in[15];
  const int*   sp1  = (const int*)d_in[16];
  const int*   col1 = (const int*)d_in[17];
  const float* val1 = (const float*)d_in[18];
  const int*   sp2  = (const int*)d_in[19];
  const int*   col2 = (const int*)d_in[20];
  const float* val2 = (const float*)d_in[21];
  const int*   sp3  = (const int*)d_in[22];
  const int*   col3 = (const int*)d_in[23];
  const float* val3 = (const float*)d_in[24];

  unsigned short* bufA = (unsigned short*)d_ws;                       // conv out / x0
  unsigned short* bufB = (unsigned short*)((char*)d_ws + 25690112);   // pool out
  unsigned short* bufC = (unsigned short*)((char*)d_ws + 77070336);   // A panels
  unsigned short* pwT  = (unsigned short*)((char*)d_ws + 128450560);  // split tables
  float* outp = (float*)d_out;

  unsigned short* h0 = pwT;            unsigned short* L0 = pwT + 172032;
  unsigned short* h1 = pwT + 65536;    unsigned short* L1 = L0 + 65536;
  unsigned short* h2 = pwT + 131072;   unsigned short* L2 = L0 + 131072;
  unsigned short* h3 = pwT + 163840;   unsigned short* L3 = L0 + 163840;

  k_prep<<<672, 256, 0, stream>>>(pw0, pw1, pw2, pw3, pwT);
  k_sample_up<<<dim3(14,16,1), 256, 0, stream>>>(uv, feat, up, bufA);

  // level 1: 784 -> 1568, 256 -> 256
  k_pool<<<1568, 256, 0, stream>>>(bufA, col3, val3, bufB, 16*256);
  k_dw<256><<<392, 256, 0, stream>>>(bufB, sp3, dw0, bufC);
  k_gemm<256,256,true><<<392, 256, 0, stream>>>(bufC, h0, L0, bufA);

  // level 2: 1568 -> 3136, 256 -> 256
  k_pool<<<3136, 256, 0, stream>>>(bufA, col2, val2, bufB, 16*256);
  k_dw<256><<<784, 256, 0, stream>>>(bufB, sp2, dw1, bufC);
  k_gemm<256,256,true><<<784, 256, 0, stream>>>(bufC, h1, L1, bufA);

  // level 3: 3136 -> 6272, 256 -> 128
  k_pool<<<6272, 256, 0, stream>>>(bufA, col1, val1, bufB, 16*256);
  k_dw<256><<<1568, 256, 0, stream>>>(bufB, sp1, dw2, bufC);
  k_gemm<256,128,true><<<1568, 256, 0, stream>>>(bufC, h2, L2, bufA);

  // level 4: 6272 -> 12544, 128 -> 64
  k_pool<<<12544, 256, 0, stream>>>(bufA, col0, val0, bufB, 16*128);
  k_dw<128><<<3136, 256, 0, stream>>>(bufB, sp0, dw3, bufC);
  k_gemm<128,64,true><<<3136, 256, 0, stream>>>(bufC, h3, L3, bufA);

  k_head<<<50176, 256, 0, stream>>>(bufA, sp0, dwh, pwh, outp, 12544);
}

// Round 8
// 596.999 us; speedup vs baseline: 1.8949x; 1.0846x over previous
//
#include <hip/hip_runtime.h>

// Activations: (vertex, batch=16, channel), channel fastest, stored FP16.
// d_ws layout:
//   bufA (fp16, conv outputs / x0)  @ 0            cap 25,690,112 B
//   bufB (fp16, pool outputs)       @ 25,690,112   cap 51,380,224 B
//   bufC (fp16, dwconv A panels)    @ 77,070,336   cap 51,380,224 B
//   pwT  (fp16 split hi/lo tables)  @ 128,450,560  688,128 B
//   bheadT (head W split hi/lo)     @ 129,138,688  16,384 B
//   z    (fp32 head partials)       @ 129,155,072  21,676,032 B
// Total 150.8 MB (ws >= 154,140,672 B proven in round 1).
//
// k_dw is two-phase over batch halves (x-major dispatch -> temporal
// separation halves the gather working set -> better L2 hit).
// Head: k_headz streaming GEMM (B[c,s*3+j]=dwh*pwh) -> z[u][s][b][j],
// then k_head2 gathers 192B contiguous (u,s) slices: 21.7 MB logical
// instead of 231 MB.
// NOTE: never raise __launch_bounds__ min-waves on MFMA kernels — round 5
// showed forced spills (WRITE_SIZE 585 MB, 20 ms dispatches).

typedef _Float16 half8 __attribute__((ext_vector_type(8)));
typedef float    f32x4 __attribute__((ext_vector_type(4)));

__device__ __forceinline__ float4 ld4(const float* p) { return *(const float4*)p; }

__device__ __forceinline__ float lo16f(unsigned u) {
  _Float16 h; unsigned short s = (unsigned short)(u & 0xffffu);
  __builtin_memcpy(&h, &s, 2); return (float)h;
}
__device__ __forceinline__ float hi16f(unsigned u) {
  _Float16 h; unsigned short s = (unsigned short)(u >> 16);
  __builtin_memcpy(&h, &s, 2); return (float)h;
}
__device__ __forceinline__ float h2f(unsigned short s) {
  _Float16 h; __builtin_memcpy(&h, &s, 2); return (float)h;
}
__device__ __forceinline__ unsigned short hbits(float v) {
  _Float16 h = (_Float16)v; unsigned short u; __builtin_memcpy(&u, &h, 2); return u;
}
__device__ __forceinline__ unsigned pk2h(float a, float b) {
  return (unsigned)hbits(a) | ((unsigned)hbits(b) << 16);
}
// split v = hi + lo*2^-11, lo pre-scaled by 2048
__device__ __forceinline__ void split2h(float v, unsigned short& h, unsigned short& l) {
  _Float16 hf = (_Float16)v;
  float hif = (float)hf;
  _Float16 lf = (_Float16)((v - hif) * 2048.0f);
  __builtin_memcpy(&h, &hf, 2); __builtin_memcpy(&l, &lf, 2);
}

// ---------------- prep: transpose+split pw -> pwT_hi / pwT_lo fp16 [CO][CI] ----------------
__global__ __launch_bounds__(256) void k_prep(
    const float* __restrict__ pw0, const float* __restrict__ pw1,
    const float* __restrict__ pw2, const float* __restrict__ pw3,
    unsigned short* __restrict__ dst)
{
  const int b = blockIdx.x, t = threadIdx.x;
  const float* src; int ci_sh, co, f, off;
  if (b < 256)      { src = pw0; ci_sh = 8; co = 256; f = b*256 + t;       off = 0; }
  else if (b < 512) { src = pw1; ci_sh = 8; co = 256; f = (b-256)*256 + t; off = 65536; }
  else if (b < 640) { src = pw2; ci_sh = 8; co = 128; f = (b-512)*256 + t; off = 131072; }
  else              { src = pw3; ci_sh = 7; co = 64;  f = (b-640)*256 + t; off = 163840; }
  const int n = f >> ci_sh, k = f & ((1 << ci_sh) - 1);
  float v = src[(size_t)k*co + n];
  unsigned short h, l; split2h(v, h, l);
  dst[off + f]          = h;
  dst[172032 + off + f] = l;
}

// ---------------- prep head W: B[c][n] = dwh[c,n/3]*pwh[c,n%3], bT [32][64] hi/lo ----------------
__global__ __launch_bounds__(256) void k_prep_head(
    const float* __restrict__ dwh, const float* __restrict__ pwh,
    unsigned short* __restrict__ dst)
{
  const int i = blockIdx.x*256 + threadIdx.x;   // 2048 = 32*64
  const int n = i >> 6, c = i & 63;
  float v = 0.f;
  if (n < 27) v = dwh[c*9 + n/3] * pwh[c*3 + n%3];
  unsigned short h, l; split2h(v, h, l);
  dst[i] = h; dst[2048 + i] = l;
}

// ---------------- fused grid-sample + upsample GEMM -> fp16 x0 ----------------
__global__ __launch_bounds__(256) void k_sample_up(
    const float* __restrict__ uv, const float* __restrict__ feat,
    const float* __restrict__ up, unsigned short* __restrict__ x0)
{
  __shared__ float feat_l[256][17];
  const int tid = threadIdx.x;
  const int b   = blockIdx.y;
  const int v0  = blockIdx.x * 56;

  const float* fr = feat + ((size_t)b*256 + tid)*16;
  #pragma unroll
  for (int i = 0; i < 16; i += 4) {
    float4 f = ld4(fr + i);
    feat_l[tid][i+0] = f.x; feat_l[tid][i+1] = f.y;
    feat_l[tid][i+2] = f.z; feat_l[tid][i+3] = f.w;
  }
  float xg[64];
  #pragma unroll
  for (int p = 0; p < 64; ++p) {
    float gx = uv[((size_t)b*64 + p)*2 + 0];
    float gy = uv[((size_t)b*64 + p)*2 + 1];
    gx = fminf(fmaxf((gx - 0.5f)*2.f, -1.f), 1.f);
    gy = fminf(fmaxf((gy - 0.5f)*2.f, -1.f), 1.f);
    float x = (gx + 1.f)*0.5f*3.f;
    float y = (gy + 1.f)*0.5f*3.f;
    float fx = floorf(x), fy = floorf(y);
    int ix0 = (int)fx, iy0 = (int)fy;
    float wx = x - fx, wy = y - fy;
    int ix1 = ix0 + 1 > 3 ? 3 : ix0 + 1;
    int iy1 = iy0 + 1 > 3 ? 3 : iy0 + 1;
    float v00 = feat_l[tid][iy0*4+ix0];
    float v01 = feat_l[tid][iy0*4+ix1];
    float v10 = feat_l[tid][iy1*4+ix0];
    float v11 = feat_l[tid][iy1*4+ix1];
    xg[p] = (1.f-wy)*((1.f-wx)*v00 + wx*v01) + wy*((1.f-wx)*v10 + wx*v11);
  }
  for (int vv = 0; vv < 56; vv += 4) {
    float a0 = 0.f, a1 = 0.f, a2 = 0.f, a3 = 0.f;
    const float* u0 = up + (size_t)(v0+vv  )*64;
    const float* u1 = up + (size_t)(v0+vv+1)*64;
    const float* u2 = up + (size_t)(v0+vv+2)*64;
    const float* u3 = up + (size_t)(v0+vv+3)*64;
    #pragma unroll
    for (int p = 0; p < 64; ++p) {
      float xv = xg[p];
      a0 += u0[p]*xv; a1 += u1[p]*xv; a2 += u2[p]*xv; a3 += u3[p]*xv;
    }
    unsigned short* o = x0 + ((size_t)(v0+vv)*16 + b)*256 + tid;
    o[0*16*256] = hbits(a0); o[1*16*256] = hbits(a1);
    o[2*16*256] = hbits(a2); o[3*16*256] = hbits(a3);
  }
}

// ---------------- mesh up-pool: fp16 -> fp16 (fp32 math) ----------------
__global__ __launch_bounds__(256) void k_pool(
    const unsigned short* __restrict__ x, const int* __restrict__ col,
    const float* __restrict__ val, unsigned short* __restrict__ out, int C16)
{
  const int v = blockIdx.x;
  const int c0 = col[3*v+0], c1 = col[3*v+1], c2 = col[3*v+2];
  const float w0 = val[3*v+0], w1 = val[3*v+1], w2 = val[3*v+2];
  const uint4* r0 = (const uint4*)(x + (size_t)c0*C16);
  const uint4* r1 = (const uint4*)(x + (size_t)c1*C16);
  const uint4* r2 = (const uint4*)(x + (size_t)c2*C16);
  uint4* o = (uint4*)(out + (size_t)v*C16);
  const int n8 = C16 >> 3;
  for (int i = threadIdx.x; i < n8; i += 256) {
    uint4 A = r0[i], B = r1[i], Cv = r2[i], R;
    R.x = pk2h(w0*lo16f(A.x)+w1*lo16f(B.x)+w2*lo16f(Cv.x),
               w0*hi16f(A.x)+w1*hi16f(B.x)+w2*hi16f(Cv.x));
    R.y = pk2h(w0*lo16f(A.y)+w1*lo16f(B.y)+w2*lo16f(Cv.y),
               w0*hi16f(A.y)+w1*hi16f(B.y)+w2*hi16f(Cv.y));
    R.z = pk2h(w0*lo16f(A.z)+w1*lo16f(B.z)+w2*lo16f(Cv.z),
               w0*hi16f(A.z)+w1*hi16f(B.z)+w2*hi16f(Cv.z));
    R.w = pk2h(w0*lo16f(A.w)+w1*lo16f(B.w)+w2*lo16f(Cv.w),
               w0*hi16f(A.w)+w1*hi16f(B.w)+w2*hi16f(Cv.w));
    o[i] = R;
  }
}

// ---------------- k_dw: two-phase spiral-gather + depthwise conv -> A panel ----------------
// grid.x = 2*nvb; first half of blocks (x-major order) does batches 0-7,
// second half batches 8-15 -> per-phase gather working set is halved.
// Block = 4 vertices x 8 batches = 32 rows x CI.
template<int CI>
__global__ __launch_bounds__(256) void k_dw(
    const unsigned short* __restrict__ pin, const int* __restrict__ idx,
    const float* __restrict__ dw, unsigned short* __restrict__ aout)
{
  constexpr int KG   = CI/8;       // channel groups of 8 (16B fp16 gather)
  constexpr int TPG  = 256/KG;     // thread row-groups
  constexpr int MPT  = 32/TPG;     // rows per thread
  constexpr int AROW = CI + 8;

  __shared__ __align__(16) unsigned short a_l[32][AROW];

  const int t    = threadIdx.x;
  const int nvb  = gridDim.x >> 1;
  const int half = (blockIdx.x >= nvb) ? 1 : 0;
  const int vb   = blockIdx.x - half*nvb;
  const int v0   = vb * 4;
  const int b0   = half * 8;

  {
    const int kg   = t & (KG - 1);
    const int mb   = (t / KG) * MPT;     // 32-row space; MPT rows stay in one vertex
    const int vloc = mb >> 3;
    int rows[9];
    #pragma unroll
    for (int s = 0; s < 9; ++s) rows[s] = idx[(v0 + vloc)*9 + s] * (16*CI);
    float dwv[72];
    #pragma unroll
    for (int j = 0; j < 8; ++j)
      #pragma unroll
      for (int s = 0; s < 9; ++s) dwv[j*9 + s] = dw[(size_t)(8*kg + j)*9 + s];

    #pragma unroll
    for (int i = 0; i < MPT; ++i) {
      const int m  = mb + i;
      const int bb = b0 + (m & 7);
      const unsigned short* base = pin + (size_t)bb*CI + 8*kg;
      float y[8];
      #pragma unroll
      for (int j = 0; j < 8; ++j) y[j] = 0.f;
      #pragma unroll
      for (int s = 0; s < 9; ++s) {
        const uint4 g = *(const uint4*)(base + rows[s]);
        y[0] += dwv[0*9+s]*lo16f(g.x); y[1] += dwv[1*9+s]*hi16f(g.x);
        y[2] += dwv[2*9+s]*lo16f(g.y); y[3] += dwv[3*9+s]*hi16f(g.y);
        y[4] += dwv[4*9+s]*lo16f(g.z); y[5] += dwv[5*9+s]*hi16f(g.z);
        y[6] += dwv[6*9+s]*lo16f(g.w); y[7] += dwv[7*9+s]*hi16f(g.w);
      }
      uint4 pkd;
      pkd.x = pk2h(y[0], y[1]); pkd.y = pk2h(y[2], y[3]);
      pkd.z = pk2h(y[4], y[5]); pkd.w = pk2h(y[6], y[7]);
      *(uint4*)&a_l[m][8*kg] = pkd;
    }
  }
  __syncthreads();

  // coalesced panel store: 32 rows x CI ushorts into full-layout panel rows
  constexpr int PR = CI/8;  // uint4 per row
  #pragma unroll
  for (int i = 0; i < (32*PR)/256; ++i) {
    const int item = t + i*256;
    const int r  = item / PR;                      // local row 0..31
    const int cp = (item % PR)*8;
    const int grow = (v0 + (r >> 3))*16 + b0 + (r & 7);
    *(uint4*)(aout + (size_t)grow*CI + cp) = *(const uint4*)&a_l[r][cp];
  }
}

// ---------------- k_gemm: streaming MFMA pointwise, D = Ah*Bh + Ah*Bl*2^-11 ----------------
template<int CI, int CO, bool RELU>
__global__ __launch_bounds__(256) void k_gemm(
    const unsigned short* __restrict__ A,
    const unsigned short* __restrict__ bhp, const unsigned short* __restrict__ blp,
    unsigned short* __restrict__ out)
{
  constexpr int NTW    = CO/64;
  constexpr int CHUNKS = CI/32;
  constexpr int OROW   = CO + 8;

  __shared__ __align__(16) unsigned short ot[64][OROW];

  const int t  = threadIdx.x;
  const size_t m0 = (size_t)blockIdx.x * 64;
  const int w = t >> 6, l = t & 15, q = (t >> 4) & 3;

  f32x4 ah[4][NTW], ax[4][NTW];
  #pragma unroll
  for (int mt = 0; mt < 4; ++mt)
    #pragma unroll
    for (int n = 0; n < NTW; ++n)
      #pragma unroll
      for (int r = 0; r < 4; ++r) { ah[mt][n][r] = 0.f; ax[mt][n][r] = 0.f; }

  #pragma unroll
  for (int c = 0; c < CHUNKS; ++c) {
    const int k0 = c*32 + q*8;
    half8 fa[4], fbh[NTW], fbl[NTW];
    #pragma unroll
    for (int mt = 0; mt < 4; ++mt)
      fa[mt] = *(const half8*)(A + (m0 + mt*16 + l)*CI + k0);
    #pragma unroll
    for (int n = 0; n < NTW; ++n) {
      const size_t boff = (size_t)((w*NTW + n)*16 + l)*CI + k0;
      fbh[n] = *(const half8*)(bhp + boff);
      fbl[n] = *(const half8*)(blp + boff);
    }
    #pragma unroll
    for (int mt = 0; mt < 4; ++mt)
      #pragma unroll
      for (int n = 0; n < NTW; ++n) {
        ah[mt][n] = __builtin_amdgcn_mfma_f32_16x16x32_f16(fa[mt], fbh[n], ah[mt][n], 0, 0, 0);
        ax[mt][n] = __builtin_amdgcn_mfma_f32_16x16x32_f16(fa[mt], fbl[n], ax[mt][n], 0, 0, 0);
      }
  }

  #pragma unroll
  for (int mt = 0; mt < 4; ++mt)
    #pragma unroll
    for (int n = 0; n < NTW; ++n) {
      const int colg = (w*NTW + n)*16 + l;
      #pragma unroll
      for (int r = 0; r < 4; ++r) {
        const int row = mt*16 + q*4 + r;
        float v = ah[mt][n][r] + ax[mt][n][r] * (1.0f/2048.0f);
        if (RELU) v = fmaxf(v, 0.f);
        ot[row][colg] = hbits(v);
      }
    }
  __syncthreads();
  constexpr int PR = CO/8;
  unsigned short* ob = out + m0*CO;
  #pragma unroll
  for (int i = 0; i < (64*PR)/256; ++i) {
    const int item = t + i*256;
    const int r  = item / PR;
    const int cp = (item % PR)*8;
    *(uint4*)(ob + (size_t)r*CO + cp) = *(const uint4*)&ot[r][cp];
  }
}

// ---------------- k_headz: streaming GEMM x(200704x64) @ W(64x32) -> z[u][s][b][j] ----------------
__global__ __launch_bounds__(256) void k_headz(
    const unsigned short* __restrict__ A,
    const unsigned short* __restrict__ bhT, const unsigned short* __restrict__ blT,
    float* __restrict__ z)
{
  __shared__ float zt[4][32][16];   // [u_loc][n][b]

  const int t = threadIdx.x;
  const size_t m0 = (size_t)blockIdx.x * 64;
  const int w = t >> 6, l = t & 15, q = (t >> 4) & 3;

  f32x4 acch[2], accl[2];
  #pragma unroll
  for (int n = 0; n < 2; ++n)
    #pragma unroll
    for (int r = 0; r < 4; ++r) { acch[n][r] = 0.f; accl[n][r] = 0.f; }

  #pragma unroll
  for (int c = 0; c < 2; ++c) {
    const int k0 = c*32 + q*8;
    half8 fa = *(const half8*)(A + (m0 + w*16 + l)*64 + k0);
    #pragma unroll
    for (int n = 0; n < 2; ++n) {
      half8 fbh = *(const half8*)(bhT + (size_t)(n*16 + l)*64 + k0);
      half8 fbl = *(const half8*)(blT + (size_t)(n*16 + l)*64 + k0);
      acch[n] = __builtin_amdgcn_mfma_f32_16x16x32_f16(fa, fbh, acch[n], 0, 0, 0);
      accl[n] = __builtin_amdgcn_mfma_f32_16x16x32_f16(fa, fbl, accl[n], 0, 0, 0);
    }
  }

  // D[row=q*4+r][col=l] : row = b, col = n-local
  #pragma unroll
  for (int n = 0; n < 2; ++n)
    #pragma unroll
    for (int r = 0; r < 4; ++r)
      zt[w][n*16 + l][q*4 + r] = acch[n][r] + accl[n][r] * (1.0f/2048.0f);
  __syncthreads();

  // write z[u][s*48 + b*3 + j] (432 floats per u, contiguous; coalesced)
  const size_t u0 = m0 >> 4;
  #pragma unroll
  for (int i = 0; i < 7; ++i) {
    const int item = t + i*256;
    if (item < 1728) {
      const int ul  = item / 432;
      const int rem = item - ul*432;
      const int s   = rem / 48;
      const int bj  = rem - s*48;
      const int b   = bj / 3;
      const int j   = bj - b*3;
      z[(u0 + ul)*432 + rem] = zt[ul][s*3 + j][b];
    }
  }
}

// ---------------- k_head2: gather-sum 9 contiguous 192B slices, out (b, v, 3) ----------------
__global__ __launch_bounds__(256) void k_head2(
    const float* __restrict__ z, const int* __restrict__ idx,
    float* __restrict__ out, int nvert)
{
  const int w    = threadIdx.x >> 6;
  const int lane = threadIdx.x & 63;
  const int v    = blockIdx.x*4 + w;
  if (lane < 48) {
    float acc = 0.f;
    #pragma unroll
    for (int s = 0; s < 9; ++s) {
      const int u = idx[v*9 + s];
      acc += z[(size_t)u*432 + s*48 + lane];
    }
    const int b = lane / 3, j = lane - b*3;
    out[((size_t)b*nvert + v)*3 + j] = acc;
  }
}

extern "C" void kernel_launch(void* const* d_in, const int* in_sizes, int n_in,
                              void* d_out, int out_size, void* d_ws, size_t ws_size,
                              hipStream_t stream)
{
  const float* uv   = (const float*)d_in[0];
  const float* feat = (const float*)d_in[1];
  const float* up   = (const float*)d_in[2];
  const float* dw0  = (const float*)d_in[3];
  const float* pw0  = (const float*)d_in[4];
  const float* dw1  = (const float*)d_in[5];
  const float* pw1  = (const float*)d_in[6];
  const float* dw2  = (const float*)d_in[7];
  const float* pw2  = (const float*)d_in[8];
  const float* dw3  = (const float*)d_in[9];
  const float* pw3  = (const float*)d_in[10];
  const float* dwh  = (const float*)d_in[11];
  const float* pwh  = (const float*)d_in[12];
  const int*   sp0  = (const int*)d_in[13];
  const int*   col0 = (const int*)d_in[14];
  const float* val0 = (const float*)d_in[15];
  const int*   sp1  = (const int*)d_in[16];
  const int*   col1 = (const int*)d_in[17];
  const float* val1 = (const float*)d_in[18];
  const int*   sp2  = (const int*)d_in[19];
  const int*   col2 = (const int*)d_in[20];
  const float* val2 = (const float*)d_in[21];
  const int*   sp3  = (const int*)d_in[22];
  const int*   col3 = (const int*)d_in[23];
  const float* val3 = (const float*)d_in[24];

  unsigned short* bufA  = (unsigned short*)d_ws;
  unsigned short* bufB  = (unsigned short*)((char*)d_ws + 25690112);
  unsigned short* bufC  = (unsigned short*)((char*)d_ws + 77070336);
  unsigned short* pwT   = (unsigned short*)((char*)d_ws + 128450560);
  unsigned short* bhead = (unsigned short*)((char*)d_ws + 129138688);
  float*          zbuf  = (float*)((char*)d_ws + 129155072);
  float* outp = (float*)d_out;

  unsigned short* h0 = pwT;            unsigned short* L0 = pwT + 172032;
  unsigned short* h1 = pwT + 65536;    unsigned short* L1 = L0 + 65536;
  unsigned short* h2 = pwT + 131072;   unsigned short* L2 = L0 + 131072;
  unsigned short* h3 = pwT + 163840;   unsigned short* L3 = L0 + 163840;
  unsigned short* hh = bhead;          unsigned short* Lh = bhead + 2048;

  k_prep<<<672, 256, 0, stream>>>(pw0, pw1, pw2, pw3, pwT);
  k_prep_head<<<8, 256, 0, stream>>>(dwh, pwh, bhead);
  k_sample_up<<<dim3(14,16,1), 256, 0, stream>>>(uv, feat, up, bufA);

  // level 1: 784 -> 1568, 256 -> 256
  k_pool<<<1568, 256, 0, stream>>>(bufA, col3, val3, bufB, 16*256);
  k_dw<256><<<784, 256, 0, stream>>>(bufB, sp3, dw0, bufC);
  k_gemm<256,256,true><<<392, 256, 0, stream>>>(bufC, h0, L0, bufA);

  // level 2: 1568 -> 3136, 256 -> 256
  k_pool<<<3136, 256, 0, stream>>>(bufA, col2, val2, bufB, 16*256);
  k_dw<256><<<1568, 256, 0, stream>>>(bufB, sp2, dw1, bufC);
  k_gemm<256,256,true><<<784, 256, 0, stream>>>(bufC, h1, L1, bufA);

  // level 3: 3136 -> 6272, 256 -> 128
  k_pool<<<6272, 256, 0, stream>>>(bufA, col1, val1, bufB, 16*256);
  k_dw<256><<<3136, 256, 0, stream>>>(bufB, sp1, dw2, bufC);
  k_gemm<256,128,true><<<1568, 256, 0, stream>>>(bufC, h2, L2, bufA);

  // level 4: 6272 -> 12544, 128 -> 64
  k_pool<<<12544, 256, 0, stream>>>(bufA, col0, val0, bufB, 16*128);
  k_dw<128><<<6272, 256, 0, stream>>>(bufB, sp0, dw3, bufC);
  k_gemm<128,64,true><<<3136, 256, 0, stream>>>(bufC, h3, L3, bufA);

  // head: streaming GEMM -> z, then contiguous gather-sum
  k_headz<<<3136, 256, 0, stream>>>(bufA, hh, Lh, zbuf);
  k_head2<<<3136, 256, 0, stream>>>(zbuf, sp0, outp, 12544);
}